// Round 15
// baseline (456.003 us; speedup 1.0000x reference)
//
#include <hip/hip_runtime.h>
#include <hip/hip_bf16.h>

#define B_ 4
#define S_ 2048
#define D_ 1024
#define H_ 16
#define HD_ 64
#define M_ (B_*S_)

typedef __bf16 bf16;
typedef bf16 bf16x8 __attribute__((ext_vector_type(8)));
typedef bf16 bf16x4 __attribute__((ext_vector_type(4)));
typedef bf16 bf16x2 __attribute__((ext_vector_type(2)));
typedef float f32x4 __attribute__((ext_vector_type(4)));
typedef unsigned u32x4 __attribute__((ext_vector_type(4)));

__device__ __forceinline__ void gload_lds16(const void* g, void* l) {
  __builtin_amdgcn_global_load_lds((const __attribute__((address_space(1))) void*)g,
                                   (__attribute__((address_space(3))) void*)l, 16, 0, 0);
}

// pack two f32 -> one u32 of 2 bf16.  Paired casts into a bf16x2 let the
// compiler fuse to a single v_cvt_pk_bf16_f32 (manual shift/or defeats it).
__device__ __forceinline__ unsigned pk2(float a, float b) {
  bf16x2 v;
  v[0] = (bf16)a; v[1] = (bf16)b;
  return __builtin_bit_cast(unsigned, v);
}

// ---------------------------------------------------------------- weights T
__global__ __launch_bounds__(256)
void wtrans_kernel(const float* __restrict__ Wq, const float* __restrict__ Wk,
                   const float* __restrict__ Wv, const float* __restrict__ Wo,
                   bf16* __restrict__ Wqt, bf16* __restrict__ Wkt,
                   bf16* __restrict__ Wvt, bf16* __restrict__ Wot) {
  __shared__ float tile[64][65];
  const float* W; bf16* Wt;
  switch (blockIdx.z) {
    case 0: W = Wq; Wt = Wqt; break;
    case 1: W = Wk; Wt = Wkt; break;
    case 2: W = Wv; Wt = Wvt; break;
    default: W = Wo; Wt = Wot; break;
  }
  int n0 = blockIdx.x * 64, k0 = blockIdx.y * 64;
  int tx = threadIdx.x & 63, ty = threadIdx.x >> 6;
#pragma unroll
  for (int i = 0; i < 16; i++) {
    int k = ty + i * 4;
    tile[k][tx] = W[(size_t)(k0 + k) * D_ + n0 + tx];
  }
  __syncthreads();
#pragma unroll
  for (int i = 0; i < 16; i++) {
    int n = ty + i * 4;
    Wt[(size_t)(n0 + n) * D_ + k0 + tx] = (bf16)tile[tx][n];
  }
}

// ---------------------------------------------------------------- qkv cast
// fp32 -> bf16 pre-pass for activations (memory-bound, ~150 MB => ~24 us).
// Fusing this into proj was tried twice (r2, r12): the in-loop load+cvt+
// ds_write chain costs MORE than this separate BW-bound pass.  Keep split.
__global__ __launch_bounds__(256)
void qkv_cvt_kernel(const float* __restrict__ q, const float* __restrict__ k,
                    const float* __restrict__ v,
                    bf16* __restrict__ qo, bf16* __restrict__ ko, bf16* __restrict__ vo) {
  const float* src; bf16* dst;
  switch (blockIdx.y) {
    case 0: src = q; dst = qo; break;
    case 1: src = k; dst = ko; break;
    default: src = v; dst = vo; break;
  }
  size_t i = ((size_t)blockIdx.x * 256 + threadIdx.x) * 8;
  f32x4 a = *(const f32x4*)(src + i);
  f32x4 b = *(const f32x4*)(src + i + 4);
  bf16x8 o;
  o[0] = (bf16)a[0]; o[1] = (bf16)a[1]; o[2] = (bf16)a[2]; o[3] = (bf16)a[3];
  o[4] = (bf16)b[0]; o[5] = (bf16)b[1]; o[6] = (bf16)b[2]; o[7] = (bf16)b[3];
  *(bf16x8*)(dst + i) = o;
}

// ---------------------------------------------------------------- QKV proj
// Pure-bf16 m97-style GEMM: BK=64, global_load_lds staging both operands,
// XOR-8 swizzle, single-buffer, 32 KB LDS (5 blocks/CU).  XCD swizzle.
// Schedule variants tried and rejected: counted-vmcnt dbuf (r7: neutral,
// 64KB LDS), T3-min 1-barrier dbuf (r8: neutral), 256^2 8-phase (r9: -10us).
#define QSCALE 0.18033688011112042f  // 1/sqrt(HD) * log2(e)

__global__ __launch_bounds__(256)
void proj_gemm_kernel(const bf16* __restrict__ Aqb, const bf16* __restrict__ Akb,
                      const bf16* __restrict__ Avb,
                      const bf16* __restrict__ Wqt, const bf16* __restrict__ Wkt,
                      const bf16* __restrict__ Wvt,
                      const float* __restrict__ bq, const float* __restrict__ bk,
                      const float* __restrict__ bv,
                      bf16* __restrict__ qb, bf16* __restrict__ kb, bf16* __restrict__ vbT) {
  __shared__ bf16 As[128 * 64];  // 16 KB
  __shared__ bf16 Bs[128 * 64];  // 16 KB
  const bf16* A; const bf16* Bt; const float* bias;
  if (blockIdx.z == 0)      { A = Aqb; Bt = Wqt; bias = bq; }
  else if (blockIdx.z == 1) { A = Akb; Bt = Wkt; bias = bk; }
  else                      { A = Avb; Bt = Wvt; bias = bv; }

  // XCD swizzle: nwg=512/slice, orig&7 == XCD; XCD c gets m-tiles [c*8,c*8+8)
  const int orig = blockIdx.y * gridDim.x + blockIdx.x;   // y*8 + x
  const int swz  = (orig & 7) * 64 + (orig >> 3);
  const int n0 = (swz & 7) * 128, m0 = (swz >> 3) * 128;

  const int tid = threadIdx.x;
  const int lane = tid & 63, w = tid >> 6;
  const int wr = w >> 1, wc = w & 1;
  const int l15 = lane & 15, quad = lane >> 4;
  const int srow = lane >> 3, schunk = lane & 7;

  f32x4 acc[4][4] = {};

  for (int kt = 0; kt < D_ / 64; kt++) {
    const int k0 = kt * 64;
#pragma unroll
    for (int t = 0; t < 4; t++) {
      int r0 = w * 32 + t * 8;
      int row = r0 + srow;
      int cg = schunk ^ (row & 7);
      gload_lds16(A + (size_t)(m0 + row) * D_ + k0 + cg * 8, &As[r0 * 64]);
      gload_lds16(Bt + (size_t)(n0 + row) * D_ + k0 + cg * 8, &Bs[r0 * 64]);
    }
    __syncthreads();

#pragma unroll
    for (int ks = 0; ks < 2; ks++) {
      bf16x8 a[4], b[4];
#pragma unroll
      for (int fm = 0; fm < 4; fm++) {
        int row = wr * 64 + fm * 16 + l15;
        a[fm] = *(const bf16x8*)(&As[row * 64 + (((ks * 4 + quad) ^ (row & 7)) * 8)]);
      }
#pragma unroll
      for (int fn = 0; fn < 4; fn++) {
        int row = wc * 64 + fn * 16 + l15;
        b[fn] = *(const bf16x8*)(&Bs[row * 64 + (((ks * 4 + quad) ^ (row & 7)) * 8)]);
      }
#pragma unroll
      for (int fm = 0; fm < 4; fm++)
#pragma unroll
        for (int fn = 0; fn < 4; fn++)
          acc[fm][fn] = __builtin_amdgcn_mfma_f32_16x16x32_bf16(a[fm], b[fn], acc[fm][fn], 0, 0, 0);
    }
    __syncthreads();
  }

  // epilogue: +bias, *scale -> bf16.  Q/K: [M][D].  V: transposed [D][M].
  if (blockIdx.z < 2) {
    bf16* C = (blockIdx.z == 0) ? qb : kb;
    float scale = (blockIdx.z == 0) ? QSCALE : 1.0f;
#pragma unroll
    for (int fm = 0; fm < 4; fm++) {
      int row = m0 + wr * 64 + fm * 16 + quad * 4;
#pragma unroll
      for (int fn = 0; fn < 4; fn++) {
        int col = n0 + wc * 64 + fn * 16 + l15;
        float bval = bias[col];
#pragma unroll
        for (int r = 0; r < 4; r++)
          C[(size_t)(row + r) * D_ + col] = (bf16)((acc[fm][fn][r] + bval) * scale);
      }
    }
  } else {
#pragma unroll
    for (int fm = 0; fm < 4; fm++) {
      int row = m0 + wr * 64 + fm * 16 + quad * 4;
#pragma unroll
      for (int fn = 0; fn < 4; fn++) {
        int col = n0 + wc * 64 + fn * 16 + l15;
        float bval = bias[col];
        bf16x4 pk;
#pragma unroll
        for (int r = 0; r < 4; r++) pk[r] = (bf16)(acc[fm][fn][r] + bval);
        *(bf16x4*)(vbT + (size_t)col * M_ + row) = pk;
      }
    }
  }
}

// ---------------------------------------------------------------- attention
// QBLK=512 (1024 threads, 16 waves): K/V staged 4 blocks/head (was 8);
// waves 0-7 stage K, waves 8-15 stage V -> ONE gload/tile/wave.  Grid 256
// = exactly 1 block/CU x 16 waves = 16 waves/CU (same residency as r14's
// 2x8), zero tail.  Per-wave code identical to r14: S^T QK ks-outer, T12
// permlane, ones-MFMA row-sum, T15 att[2], Vs ring-3.
#define NT_ (S_ / 64)

__global__ __launch_bounds__(1024)
void attn_kernel(const bf16* __restrict__ qb, const bf16* __restrict__ kb,
                 const bf16* __restrict__ vbT, bf16* __restrict__ ctxb) {
  __shared__ bf16 Ks[2][64 * 64];   // 16 KB
  __shared__ bf16 Vs[3][64 * 64];   // 24 KB

  // nwg = 256, cpx = 32; orig&7 == wgid%8 == XCD; bijective.
  // XCD c gets swz in [c*32,(c+1)*32) -> heads [c*8, c*8+8): 8 heads/XCD.
  const int orig = blockIdx.y * gridDim.x + blockIdx.x;   // bh*4 + x
  const int swz  = (orig & 7) * 32 + (orig >> 3);
  const int bh = swz >> 2;
  const int b = bh >> 4, h = bh & 15;
  const int q0 = (swz & 3) * 512;

  const int tid = threadIdx.x, lane = tid & 63, w = tid >> 6;   // w: 0..15
  const int l15 = lane & 15, quad = lane >> 4;

  const size_t baseQ = ((size_t)(b * S_ + q0)) * D_ + h * HD_;

  // Q fragments direct from global (pre-scaled by log2e/8); wave w owns
  // q-rows [w*32, w*32+32) of this 512-row block.
  bf16x8 qf[2][2];
#pragma unroll
  for (int fm = 0; fm < 2; fm++)
#pragma unroll
    for (int ks = 0; ks < 2; ks++)
      qf[fm][ks] = *(const bf16x8*)(qb + baseQ + (size_t)(w * 32 + fm * 16 + l15) * D_ + ks * 32 + quad * 8);

  bf16x8 vones;
#pragma unroll
  for (int i = 0; i < 8; i++) vones[i] = (bf16)1.0f;

  f32x4 o[2][4] = {};
  f32x4 o_l[2] = {};   // row-sum accumulator (all 16 cols identical)

  const int srow_i = lane >> 3;
  const int schunk = lane & 7;

  // stage tile kt: waves 0-7 -> Ks[kt&1], waves 8-15 -> Vs[kt%3].
  // Each wave: ONE gload (64 lanes x 16B = 8 rows x 128B).
  auto stage = [&](int kt) {
    if (kt >= NT_) return;
    const int kbuf = kt & 1, vbuf = kt % 3;
    if (w < 8) {
      const int r0 = w * 8;
      const int row = r0 + srow_i;
      const int c = schunk ^ (row & 7);
      const bf16* gK = kb + ((size_t)(b * S_ + kt * 64 + row)) * D_ + h * 64 + c * 8;
      gload_lds16(gK, &Ks[kbuf][r0 * 64]);
    } else {
      const int r0 = (w - 8) * 8;
      const int row = r0 + srow_i;
      const int c = schunk ^ (row & 7);
      const bf16* gV = vbT + ((size_t)(h * 64 + row)) * M_ + b * S_ + kt * 64 + c * 8;
      gload_lds16(gV, &Vs[vbuf][r0 * 64]);
    }
  };

  // QK^T for tile kt into st (zeroed here), reading Ks[kbuf].
  // ks-outer: all 8 independent MFMAs of ks=0 issue before ks=1's dependents.
  auto QK = [&](f32x4 (&st)[4][2], int kbuf) {
#pragma unroll
    for (int fk = 0; fk < 4; fk++)
#pragma unroll
      for (int fq = 0; fq < 2; fq++) st[fk][fq] = f32x4{};
    __builtin_amdgcn_s_setprio(1);
#pragma unroll
    for (int ks = 0; ks < 2; ks++) {
#pragma unroll
      for (int fk = 0; fk < 4; fk++) {
        const int key = fk * 16 + l15;
        bf16x8 kf = *(const bf16x8*)(&Ks[kbuf][key * 64 + (((ks * 4 + quad) ^ (key & 7)) * 8)]);
#pragma unroll
        for (int fq = 0; fq < 2; fq++)
          st[fk][fq] = __builtin_amdgcn_mfma_f32_16x16x32_bf16(kf, qf[fq][ks], st[fk][fq], 0, 0, 0);
      }
    }
    __builtin_amdgcn_s_setprio(0);
  };

  // finish tile: exp2, pack+permlane to PV A-layout, PV + ones-MFMA.
  auto FIN = [&](f32x4 (&st)[4][2], int vbuf) {
#pragma unroll
    for (int fk = 0; fk < 4; fk++)
#pragma unroll
      for (int fq = 0; fq < 2; fq++) {
        st[fk][fq][0] = __builtin_amdgcn_exp2f(st[fk][fq][0]);
        st[fk][fq][1] = __builtin_amdgcn_exp2f(st[fk][fq][1]);
        st[fk][fq][2] = __builtin_amdgcn_exp2f(st[fk][fq][2]);
        st[fk][fq][3] = __builtin_amdgcn_exp2f(st[fk][fq][3]);
      }
#pragma unroll
    for (int ks2 = 0; ks2 < 2; ks2++) {
      bf16x8 pf[2], vf[4];
#pragma unroll
      for (int fm = 0; fm < 2; fm++) {
        unsigned A0 = pk2(st[2 * ks2][fm][0], st[2 * ks2][fm][1]);
        unsigned A1 = pk2(st[2 * ks2][fm][2], st[2 * ks2][fm][3]);
        unsigned B0 = pk2(st[2 * ks2 + 1][fm][0], st[2 * ks2 + 1][fm][1]);
        unsigned B1 = pk2(st[2 * ks2 + 1][fm][2], st[2 * ks2 + 1][fm][3]);
        auto s0 = __builtin_amdgcn_permlane32_swap(A0, B0, false, false);
        auto s1 = __builtin_amdgcn_permlane32_swap(A1, B1, false, false);
        auto t0 = __builtin_amdgcn_permlane16_swap(s0[0], s0[1], false, false);
        auto t1 = __builtin_amdgcn_permlane16_swap(s1[0], s1[1], false, false);
        u32x4 wv;
        wv[0] = t0[0]; wv[1] = t1[0]; wv[2] = t0[1]; wv[3] = t1[1];
        pf[fm] = __builtin_bit_cast(bf16x8, wv);
      }
#pragma unroll
      for (int fd = 0; fd < 4; fd++) {
        const int d = fd * 16 + l15;
        vf[fd] = *(const bf16x8*)(&Vs[vbuf][d * 64 + (((ks2 * 4 + quad) ^ (d & 7)) * 8)]);
      }
      __builtin_amdgcn_s_setprio(1);
#pragma unroll
      for (int fm = 0; fm < 2; fm++) {
#pragma unroll
        for (int fd = 0; fd < 4; fd++)
          o[fm][fd] = __builtin_amdgcn_mfma_f32_16x16x32_bf16(pf[fm], vf[fd], o[fm][fd], 0, 0, 0);
        o_l[fm] = __builtin_amdgcn_mfma_f32_16x16x32_bf16(pf[fm], vones, o_l[fm], 0, 0, 0);
      }
      __builtin_amdgcn_s_setprio(0);
    }
  };

  f32x4 stA[4][2], stB[4][2];

  stage(0);
  __syncthreads();

  // unroll-2 pipeline: phase A: S(t+1) | QK(t)->stA | FIN(t-1)[stB]
  //                    phase B: S(t+2) | QK(t+1)->stB | FIN(t)[stA]
  for (int i = 0; i < NT_ / 2; i++) {
    const int t = 2 * i;
    stage(t + 1);
    QK(stA, t & 1);
    if (i > 0) FIN(stB, (t - 1) % 3);
    __syncthreads();
    stage(t + 2);
    QK(stB, (t + 1) & 1);
    FIN(stA, t % 3);
    __syncthreads();
  }
  FIN(stB, (NT_ - 1) % 3);

  // epilogue: o_l[fm][r] is the row-sum for q-row = w*32+fm*16+quad*4+r.
#pragma unroll
  for (int fm = 0; fm < 2; fm++) {
#pragma unroll
    for (int r = 0; r < 4; r++) {
      float inv = 1.0f / o_l[fm][r];
      int row = w * 32 + fm * 16 + quad * 4 + r;
#pragma unroll
      for (int fd = 0; fd < 4; fd++)
        ctxb[baseQ + (size_t)row * D_ + fd * 16 + l15] = (bf16)(o[fm][fd][r] * inv);
    }
  }
}

// ---------------------------------------------------------------- out proj
// m97-style bf16 GEMM: BK=64, global_load_lds staging, XOR-8 swizzle.
// Single-buffer.  XCD-aware block swizzle.
__global__ __launch_bounds__(256)
void out_gemm_kernel(const bf16* __restrict__ A, const bf16* __restrict__ Bt,
                     const float* __restrict__ bias, float* __restrict__ Cout) {
  __shared__ bf16 As[128 * 64];
  __shared__ bf16 Bs[128 * 64];
  const int orig = blockIdx.y * gridDim.x + blockIdx.x;   // y*8 + x, nwg=512
  const int swz  = (orig & 7) * 64 + (orig >> 3);
  const int n0 = (swz & 7) * 128, m0 = (swz >> 3) * 128;

  const int tid = threadIdx.x;
  const int lane = tid & 63, w = tid >> 6;
  const int wr = w >> 1, wc = w & 1;
  const int l15 = lane & 15, quad = lane >> 4;
  const int srow = lane >> 3, schunk = lane & 7;

  f32x4 acc[4][4] = {};

  for (int kt = 0; kt < D_ / 64; kt++) {
    const int k0 = kt * 64;
#pragma unroll
    for (int t = 0; t < 4; t++) {
      int r0 = w * 32 + t * 8;
      int row = r0 + srow;
      int cg = schunk ^ (row & 7);
      gload_lds16(A + (size_t)(m0 + row) * D_ + k0 + cg * 8, &As[r0 * 64]);
      gload_lds16(Bt + (size_t)(n0 + row) * D_ + k0 + cg * 8, &Bs[r0 * 64]);
    }
    __syncthreads();

#pragma unroll
    for (int ks = 0; ks < 2; ks++) {
      bf16x8 a[4], b[4];
#pragma unroll
      for (int fm = 0; fm < 4; fm++) {
        int row = wr * 64 + fm * 16 + l15;
        a[fm] = *(const bf16x8*)(&As[row * 64 + (((ks * 4 + quad) ^ (row & 7)) * 8)]);
      }
#pragma unroll
      for (int fn = 0; fn < 4; fn++) {
        int row = wc * 64 + fn * 16 + l15;
        b[fn] = *(const bf16x8*)(&Bs[row * 64 + (((ks * 4 + quad) ^ (row & 7)) * 8)]);
      }
#pragma unroll
      for (int fm = 0; fm < 4; fm++)
#pragma unroll
        for (int fn = 0; fn < 4; fn++)
          acc[fm][fn] = __builtin_amdgcn_mfma_f32_16x16x32_bf16(a[fm], b[fn], acc[fm][fn], 0, 0, 0);
    }
    __syncthreads();
  }
#pragma unroll
  for (int fm = 0; fm < 4; fm++) {
    int row = m0 + wr * 64 + fm * 16 + quad * 4;
#pragma unroll
    for (int fn = 0; fn < 4; fn++) {
      int col = n0 + wc * 64 + fn * 16 + l15;
      float bval = bias[col];
#pragma unroll
      for (int r = 0; r < 4; r++)
        Cout[(size_t)(row + r) * D_ + col] = acc[fm][fn][r] + bval;
    }
  }
}

// ---------------------------------------------------------------- launch
extern "C" void kernel_launch(void* const* d_in, const int* in_sizes, int n_in,
                              void* d_out, int out_size, void* d_ws, size_t ws_size,
                              hipStream_t stream) {
  const float* query = (const float*)d_in[0];
  const float* key   = (const float*)d_in[1];
  const float* value = (const float*)d_in[2];
  const float* Wq = (const float*)d_in[3];
  const float* bq = (const float*)d_in[4];
  const float* Wk = (const float*)d_in[5];
  const float* bk = (const float*)d_in[6];
  const float* Wv = (const float*)d_in[7];
  const float* bv = (const float*)d_in[8];
  const float* Wo = (const float*)d_in[9];
  const float* bo = (const float*)d_in[10];
  float* out = (float*)d_out;

  char* ws = (char*)d_ws;
  const size_t WT_BYTES = (size_t)D_ * D_ * sizeof(bf16);   // 2 MB
  const size_t MD_BYTES = (size_t)M_ * D_ * sizeof(bf16);   // 16 MB
  bf16* Wqt  = (bf16*)(ws);
  bf16* Wkt  = (bf16*)(ws + WT_BYTES);
  bf16* Wvt  = (bf16*)(ws + 2 * WT_BYTES);
  bf16* Wot  = (bf16*)(ws + 3 * WT_BYTES);
  bf16* qb   = (bf16*)(ws + 4 * WT_BYTES);
  bf16* kb   = (bf16*)(ws + 4 * WT_BYTES + MD_BYTES);
  bf16* vbT  = (bf16*)(ws + 4 * WT_BYTES + 2 * MD_BYTES);
  bf16* ctxb = (bf16*)(ws + 4 * WT_BYTES + 3 * MD_BYTES);
  // converted activations: qcv aliases ctxb (dead until attn writes it,
  // which is stream-ordered after proj has consumed qcv).
  bf16* qcv  = ctxb;
  bf16* kcv  = (bf16*)(ws + 4 * WT_BYTES + 4 * MD_BYTES);
  bf16* vcv  = (bf16*)(ws + 4 * WT_BYTES + 5 * MD_BYTES);

  wtrans_kernel<<<dim3(D_ / 64, D_ / 64, 4), 256, 0, stream>>>(
      Wq, Wk, Wv, Wo, Wqt, Wkt, Wvt, Wot);

  qkv_cvt_kernel<<<dim3((size_t)M_ * D_ / 2048, 3), 256, 0, stream>>>(
      query, key, value, qcv, kcv, vcv);

  proj_gemm_kernel<<<dim3(D_ / 128, M_ / 128, 3), 256, 0, stream>>>(
      qcv, kcv, vcv, Wqt, Wkt, Wvt, bq, bk, bv, qb, kb, vbT);

  attn_kernel<<<dim3(S_ / 512, B_ * H_), 1024, 0, stream>>>(qb, kb, vbT, ctxb);

  out_gemm_kernel<<<dim3(D_ / 128, M_ / 128), 256, 0, stream>>>(ctxb, Wot, bo, out);
}

// Round 16
// 330.305 us; speedup vs baseline: 1.3806x; 1.3806x over previous
//
#include <hip/hip_runtime.h>
#include <hip/hip_bf16.h>

#define B_ 4
#define S_ 2048
#define D_ 1024
#define H_ 16
#define HD_ 64
#define M_ (B_*S_)

typedef __bf16 bf16;
typedef bf16 bf16x8 __attribute__((ext_vector_type(8)));
typedef bf16 bf16x4 __attribute__((ext_vector_type(4)));
typedef bf16 bf16x2 __attribute__((ext_vector_type(2)));
typedef float f32x4 __attribute__((ext_vector_type(4)));
typedef unsigned u32x4 __attribute__((ext_vector_type(4)));

__device__ __forceinline__ void gload_lds16(const void* g, void* l) {
  __builtin_amdgcn_global_load_lds((const __attribute__((address_space(1))) void*)g,
                                   (__attribute__((address_space(3))) void*)l, 16, 0, 0);
}

// pack two f32 -> one u32 of 2 bf16.  Paired casts into a bf16x2 let the
// compiler fuse to a single v_cvt_pk_bf16_f32 (manual shift/or defeats it).
__device__ __forceinline__ unsigned pk2(float a, float b) {
  bf16x2 v;
  v[0] = (bf16)a; v[1] = (bf16)b;
  return __builtin_bit_cast(unsigned, v);
}

// ---------------------------------------------------------------- weights T
__global__ __launch_bounds__(256)
void wtrans_kernel(const float* __restrict__ Wq, const float* __restrict__ Wk,
                   const float* __restrict__ Wv, const float* __restrict__ Wo,
                   bf16* __restrict__ Wqt, bf16* __restrict__ Wkt,
                   bf16* __restrict__ Wvt, bf16* __restrict__ Wot) {
  __shared__ float tile[64][65];
  const float* W; bf16* Wt;
  switch (blockIdx.z) {
    case 0: W = Wq; Wt = Wqt; break;
    case 1: W = Wk; Wt = Wkt; break;
    case 2: W = Wv; Wt = Wvt; break;
    default: W = Wo; Wt = Wot; break;
  }
  int n0 = blockIdx.x * 64, k0 = blockIdx.y * 64;
  int tx = threadIdx.x & 63, ty = threadIdx.x >> 6;
#pragma unroll
  for (int i = 0; i < 16; i++) {
    int k = ty + i * 4;
    tile[k][tx] = W[(size_t)(k0 + k) * D_ + n0 + tx];
  }
  __syncthreads();
#pragma unroll
  for (int i = 0; i < 16; i++) {
    int n = ty + i * 4;
    Wt[(size_t)(n0 + n) * D_ + k0 + tx] = (bf16)tile[tx][n];
  }
}

// ---------------------------------------------------------------- qkv cast
// fp32 -> bf16 pre-pass for activations (memory-bound, ~150 MB => ~24 us).
// Fusing this into proj was tried twice (r2, r12): the in-loop load+cvt+
// ds_write chain costs MORE than this separate BW-bound pass.  Keep split.
__global__ __launch_bounds__(256)
void qkv_cvt_kernel(const float* __restrict__ q, const float* __restrict__ k,
                    const float* __restrict__ v,
                    bf16* __restrict__ qo, bf16* __restrict__ ko, bf16* __restrict__ vo) {
  const float* src; bf16* dst;
  switch (blockIdx.y) {
    case 0: src = q; dst = qo; break;
    case 1: src = k; dst = ko; break;
    default: src = v; dst = vo; break;
  }
  size_t i = ((size_t)blockIdx.x * 256 + threadIdx.x) * 8;
  f32x4 a = *(const f32x4*)(src + i);
  f32x4 b = *(const f32x4*)(src + i + 4);
  bf16x8 o;
  o[0] = (bf16)a[0]; o[1] = (bf16)a[1]; o[2] = (bf16)a[2]; o[3] = (bf16)a[3];
  o[4] = (bf16)b[0]; o[5] = (bf16)b[1]; o[6] = (bf16)b[2]; o[7] = (bf16)b[3];
  *(bf16x8*)(dst + i) = o;
}

// ---------------------------------------------------------------- QKV proj
// Pure-bf16 m97-style GEMM: BK=64, global_load_lds staging both operands,
// XOR-8 swizzle, single-buffer, 32 KB LDS (5 blocks/CU).  XCD swizzle.
// Schedule variants tried and rejected: counted-vmcnt dbuf (r7: neutral,
// 64KB LDS), T3-min 1-barrier dbuf (r8: neutral), 256^2 8-phase (r9: -10us).
#define QSCALE 0.18033688011112042f  // 1/sqrt(HD) * log2(e)

__global__ __launch_bounds__(256)
void proj_gemm_kernel(const bf16* __restrict__ Aqb, const bf16* __restrict__ Akb,
                      const bf16* __restrict__ Avb,
                      const bf16* __restrict__ Wqt, const bf16* __restrict__ Wkt,
                      const bf16* __restrict__ Wvt,
                      const float* __restrict__ bq, const float* __restrict__ bk,
                      const float* __restrict__ bv,
                      bf16* __restrict__ qb, bf16* __restrict__ kb, bf16* __restrict__ vbT) {
  __shared__ bf16 As[128 * 64];  // 16 KB
  __shared__ bf16 Bs[128 * 64];  // 16 KB
  const bf16* A; const bf16* Bt; const float* bias;
  if (blockIdx.z == 0)      { A = Aqb; Bt = Wqt; bias = bq; }
  else if (blockIdx.z == 1) { A = Akb; Bt = Wkt; bias = bk; }
  else                      { A = Avb; Bt = Wvt; bias = bv; }

  // XCD swizzle: nwg=512/slice, orig&7 == XCD; XCD c gets m-tiles [c*8,c*8+8)
  const int orig = blockIdx.y * gridDim.x + blockIdx.x;   // y*8 + x
  const int swz  = (orig & 7) * 64 + (orig >> 3);
  const int n0 = (swz & 7) * 128, m0 = (swz >> 3) * 128;

  const int tid = threadIdx.x;
  const int lane = tid & 63, w = tid >> 6;
  const int wr = w >> 1, wc = w & 1;
  const int l15 = lane & 15, quad = lane >> 4;
  const int srow = lane >> 3, schunk = lane & 7;

  f32x4 acc[4][4] = {};

  for (int kt = 0; kt < D_ / 64; kt++) {
    const int k0 = kt * 64;
#pragma unroll
    for (int t = 0; t < 4; t++) {
      int r0 = w * 32 + t * 8;
      int row = r0 + srow;
      int cg = schunk ^ (row & 7);
      gload_lds16(A + (size_t)(m0 + row) * D_ + k0 + cg * 8, &As[r0 * 64]);
      gload_lds16(Bt + (size_t)(n0 + row) * D_ + k0 + cg * 8, &Bs[r0 * 64]);
    }
    __syncthreads();

#pragma unroll
    for (int ks = 0; ks < 2; ks++) {
      bf16x8 a[4], b[4];
#pragma unroll
      for (int fm = 0; fm < 4; fm++) {
        int row = wr * 64 + fm * 16 + l15;
        a[fm] = *(const bf16x8*)(&As[row * 64 + (((ks * 4 + quad) ^ (row & 7)) * 8)]);
      }
#pragma unroll
      for (int fn = 0; fn < 4; fn++) {
        int row = wc * 64 + fn * 16 + l15;
        b[fn] = *(const bf16x8*)(&Bs[row * 64 + (((ks * 4 + quad) ^ (row & 7)) * 8)]);
      }
#pragma unroll
      for (int fm = 0; fm < 4; fm++)
#pragma unroll
        for (int fn = 0; fn < 4; fn++)
          acc[fm][fn] = __builtin_amdgcn_mfma_f32_16x16x32_bf16(a[fm], b[fn], acc[fm][fn], 0, 0, 0);
    }
    __syncthreads();
  }

  // epilogue: +bias, *scale -> bf16.  Q/K: [M][D].  V: transposed [D][M].
  if (blockIdx.z < 2) {
    bf16* C = (blockIdx.z == 0) ? qb : kb;
    float scale = (blockIdx.z == 0) ? QSCALE : 1.0f;
#pragma unroll
    for (int fm = 0; fm < 4; fm++) {
      int row = m0 + wr * 64 + fm * 16 + quad * 4;
#pragma unroll
      for (int fn = 0; fn < 4; fn++) {
        int col = n0 + wc * 64 + fn * 16 + l15;
        float bval = bias[col];
#pragma unroll
        for (int r = 0; r < 4; r++)
          C[(size_t)(row + r) * D_ + col] = (bf16)((acc[fm][fn][r] + bval) * scale);
      }
    }
  } else {
#pragma unroll
    for (int fm = 0; fm < 4; fm++) {
      int row = m0 + wr * 64 + fm * 16 + quad * 4;
#pragma unroll
      for (int fn = 0; fn < 4; fn++) {
        int col = n0 + wc * 64 + fn * 16 + l15;
        float bval = bias[col];
        bf16x4 pk;
#pragma unroll
        for (int r = 0; r < 4; r++) pk[r] = (bf16)(acc[fm][fn][r] + bval);
        *(bf16x4*)(vbT + (size_t)col * M_ + row) = pk;
      }
    }
  }
}

// ---------------------------------------------------------------- attention
// QBLK=256 (512 threads, 8 waves) — session-best config (r14: 89.1 us).
// QBLK=512 (r15) spilled: __launch_bounds__(1024) caps VGPR at 64 < the
// ~116 the wave state needs -> 418 MB scratch writes, 215 us.  Keep 512thr.
// Per-wave code: S^T QK ks-outer (dependent MFMA pairs separated by 7
// independents — r10's fused form cost +10us), T12 permlane P-redistribute,
// ones-MFMA row-sum, T15 att[2] double-pipeline, Vs ring-3, XCD swizzle.
#define NT_ (S_ / 64)

__global__ __launch_bounds__(512)
void attn_kernel(const bf16* __restrict__ qb, const bf16* __restrict__ kb,
                 const bf16* __restrict__ vbT, bf16* __restrict__ ctxb) {
  __shared__ bf16 Ks[2][64 * 64];   // 16 KB
  __shared__ bf16 Vs[3][64 * 64];   // 24 KB

  // nwg = 512, cpx = 64; orig&7 == wgid%8 == XCD; bijective.
  // XCD c gets swz in [c*64,(c+1)*64) -> heads [c*8, c*8+8): 8 heads/XCD.
  const int orig = blockIdx.y * gridDim.x + blockIdx.x;   // bh*8 + x
  const int swz  = (orig & 7) * 64 + (orig >> 3);
  const int bh = swz >> 3;
  const int b = bh >> 4, h = bh & 15;
  const int q0 = (swz & 7) * 256;

  const int tid = threadIdx.x, lane = tid & 63, w = tid >> 6;   // w: 0..7
  const int l15 = lane & 15, quad = lane >> 4;

  const size_t baseQ = ((size_t)(b * S_ + q0)) * D_ + h * HD_;

  // Q fragments direct from global (pre-scaled by log2e/8); wave w owns
  // q-rows [w*32, w*32+32) of this 256-row block.
  bf16x8 qf[2][2];
#pragma unroll
  for (int fm = 0; fm < 2; fm++)
#pragma unroll
    for (int ks = 0; ks < 2; ks++)
      qf[fm][ks] = *(const bf16x8*)(qb + baseQ + (size_t)(w * 32 + fm * 16 + l15) * D_ + ks * 32 + quad * 8);

  bf16x8 vones;
#pragma unroll
  for (int i = 0; i < 8; i++) vones[i] = (bf16)1.0f;

  f32x4 o[2][4] = {};
  f32x4 o_l[2] = {};   // row-sum accumulator (all 16 cols identical)

  const int srow_i = lane >> 3;
  const int schunk = lane & 7;

  // stage tile kt: K -> Ks[kt&1], V -> Vs[kt%3].  8 waves x 8 rows = 64.
  auto stage = [&](int kt) {
    if (kt >= NT_) return;
    const int kbuf = kt & 1, vbuf = kt % 3;
    const int r0 = w * 8;
    const int row = r0 + srow_i;
    const int c = schunk ^ (row & 7);
    const bf16* gK = kb + ((size_t)(b * S_ + kt * 64 + row)) * D_ + h * 64 + c * 8;
    gload_lds16(gK, &Ks[kbuf][r0 * 64]);
    const bf16* gV = vbT + ((size_t)(h * 64 + row)) * M_ + b * S_ + kt * 64 + c * 8;
    gload_lds16(gV, &Vs[vbuf][r0 * 64]);
  };

  // QK^T for tile kt into st (zeroed here), reading Ks[kbuf].
  // ks-outer: all 8 independent MFMAs of ks=0 issue before ks=1's dependents.
  auto QK = [&](f32x4 (&st)[4][2], int kbuf) {
#pragma unroll
    for (int fk = 0; fk < 4; fk++)
#pragma unroll
      for (int fq = 0; fq < 2; fq++) st[fk][fq] = f32x4{};
    __builtin_amdgcn_s_setprio(1);
#pragma unroll
    for (int ks = 0; ks < 2; ks++) {
#pragma unroll
      for (int fk = 0; fk < 4; fk++) {
        const int key = fk * 16 + l15;
        bf16x8 kf = *(const bf16x8*)(&Ks[kbuf][key * 64 + (((ks * 4 + quad) ^ (key & 7)) * 8)]);
#pragma unroll
        for (int fq = 0; fq < 2; fq++)
          st[fk][fq] = __builtin_amdgcn_mfma_f32_16x16x32_bf16(kf, qf[fq][ks], st[fk][fq], 0, 0, 0);
      }
    }
    __builtin_amdgcn_s_setprio(0);
  };

  // finish tile: exp2, pack+permlane to PV A-layout, PV + ones-MFMA.
  auto FIN = [&](f32x4 (&st)[4][2], int vbuf) {
#pragma unroll
    for (int fk = 0; fk < 4; fk++)
#pragma unroll
      for (int fq = 0; fq < 2; fq++) {
        st[fk][fq][0] = __builtin_amdgcn_exp2f(st[fk][fq][0]);
        st[fk][fq][1] = __builtin_amdgcn_exp2f(st[fk][fq][1]);
        st[fk][fq][2] = __builtin_amdgcn_exp2f(st[fk][fq][2]);
        st[fk][fq][3] = __builtin_amdgcn_exp2f(st[fk][fq][3]);
      }
#pragma unroll
    for (int ks2 = 0; ks2 < 2; ks2++) {
      bf16x8 pf[2], vf[4];
#pragma unroll
      for (int fm = 0; fm < 2; fm++) {
        unsigned A0 = pk2(st[2 * ks2][fm][0], st[2 * ks2][fm][1]);
        unsigned A1 = pk2(st[2 * ks2][fm][2], st[2 * ks2][fm][3]);
        unsigned B0 = pk2(st[2 * ks2 + 1][fm][0], st[2 * ks2 + 1][fm][1]);
        unsigned B1 = pk2(st[2 * ks2 + 1][fm][2], st[2 * ks2 + 1][fm][3]);
        auto s0 = __builtin_amdgcn_permlane32_swap(A0, B0, false, false);
        auto s1 = __builtin_amdgcn_permlane32_swap(A1, B1, false, false);
        auto t0 = __builtin_amdgcn_permlane16_swap(s0[0], s0[1], false, false);
        auto t1 = __builtin_amdgcn_permlane16_swap(s1[0], s1[1], false, false);
        u32x4 wv;
        wv[0] = t0[0]; wv[1] = t1[0]; wv[2] = t0[1]; wv[3] = t1[1];
        pf[fm] = __builtin_bit_cast(bf16x8, wv);
      }
#pragma unroll
      for (int fd = 0; fd < 4; fd++) {
        const int d = fd * 16 + l15;
        vf[fd] = *(const bf16x8*)(&Vs[vbuf][d * 64 + (((ks2 * 4 + quad) ^ (d & 7)) * 8)]);
      }
      __builtin_amdgcn_s_setprio(1);
#pragma unroll
      for (int fm = 0; fm < 2; fm++) {
#pragma unroll
        for (int fd = 0; fd < 4; fd++)
          o[fm][fd] = __builtin_amdgcn_mfma_f32_16x16x32_bf16(pf[fm], vf[fd], o[fm][fd], 0, 0, 0);
        o_l[fm] = __builtin_amdgcn_mfma_f32_16x16x32_bf16(pf[fm], vones, o_l[fm], 0, 0, 0);
      }
      __builtin_amdgcn_s_setprio(0);
    }
  };

  f32x4 stA[4][2], stB[4][2];

  stage(0);
  __syncthreads();

  // unroll-2 pipeline: phase A: S(t+1) | QK(t)->stA | FIN(t-1)[stB]
  //                    phase B: S(t+2) | QK(t+1)->stB | FIN(t)[stA]
  for (int i = 0; i < NT_ / 2; i++) {
    const int t = 2 * i;
    stage(t + 1);
    QK(stA, t & 1);
    if (i > 0) FIN(stB, (t - 1) % 3);
    __syncthreads();
    stage(t + 2);
    QK(stB, (t + 1) & 1);
    FIN(stA, t % 3);
    __syncthreads();
  }
  FIN(stB, (NT_ - 1) % 3);

  // epilogue: o_l[fm][r] is the row-sum for q-row = w*32+fm*16+quad*4+r.
#pragma unroll
  for (int fm = 0; fm < 2; fm++) {
#pragma unroll
    for (int r = 0; r < 4; r++) {
      float inv = 1.0f / o_l[fm][r];
      int row = w * 32 + fm * 16 + quad * 4 + r;
#pragma unroll
      for (int fd = 0; fd < 4; fd++)
        ctxb[baseQ + (size_t)row * D_ + fd * 16 + l15] = (bf16)(o[fm][fd][r] * inv);
    }
  }
}

// ---------------------------------------------------------------- out proj
// m97-style bf16 GEMM: BK=64, global_load_lds staging, XOR-8 swizzle.
// Single-buffer.  XCD-aware block swizzle.
__global__ __launch_bounds__(256)
void out_gemm_kernel(const bf16* __restrict__ A, const bf16* __restrict__ Bt,
                     const float* __restrict__ bias, float* __restrict__ Cout) {
  __shared__ bf16 As[128 * 64];
  __shared__ bf16 Bs[128 * 64];
  const int orig = blockIdx.y * gridDim.x + blockIdx.x;   // y*8 + x, nwg=512
  const int swz  = (orig & 7) * 64 + (orig >> 3);
  const int n0 = (swz & 7) * 128, m0 = (swz >> 3) * 128;

  const int tid = threadIdx.x;
  const int lane = tid & 63, w = tid >> 6;
  const int wr = w >> 1, wc = w & 1;
  const int l15 = lane & 15, quad = lane >> 4;
  const int srow = lane >> 3, schunk = lane & 7;

  f32x4 acc[4][4] = {};

  for (int kt = 0; kt < D_ / 64; kt++) {
    const int k0 = kt * 64;
#pragma unroll
    for (int t = 0; t < 4; t++) {
      int r0 = w * 32 + t * 8;
      int row = r0 + srow;
      int cg = schunk ^ (row & 7);
      gload_lds16(A + (size_t)(m0 + row) * D_ + k0 + cg * 8, &As[r0 * 64]);
      gload_lds16(Bt + (size_t)(n0 + row) * D_ + k0 + cg * 8, &Bs[r0 * 64]);
    }
    __syncthreads();

#pragma unroll
    for (int ks = 0; ks < 2; ks++) {
      bf16x8 a[4], b[4];
#pragma unroll
      for (int fm = 0; fm < 4; fm++) {
        int row = wr * 64 + fm * 16 + l15;
        a[fm] = *(const bf16x8*)(&As[row * 64 + (((ks * 4 + quad) ^ (row & 7)) * 8)]);
      }
#pragma unroll
      for (int fn = 0; fn < 4; fn++) {
        int row = wc * 64 + fn * 16 + l15;
        b[fn] = *(const bf16x8*)(&Bs[row * 64 + (((ks * 4 + quad) ^ (row & 7)) * 8)]);
      }
#pragma unroll
      for (int fm = 0; fm < 4; fm++)
#pragma unroll
        for (int fn = 0; fn < 4; fn++)
          acc[fm][fn] = __builtin_amdgcn_mfma_f32_16x16x32_bf16(a[fm], b[fn], acc[fm][fn], 0, 0, 0);
    }
    __syncthreads();
  }
#pragma unroll
  for (int fm = 0; fm < 4; fm++) {
    int row = m0 + wr * 64 + fm * 16 + quad * 4;
#pragma unroll
    for (int fn = 0; fn < 4; fn++) {
      int col = n0 + wc * 64 + fn * 16 + l15;
      float bval = bias[col];
#pragma unroll
      for (int r = 0; r < 4; r++)
        Cout[(size_t)(row + r) * D_ + col] = acc[fm][fn][r] + bval;
    }
  }
}

// ---------------------------------------------------------------- launch
extern "C" void kernel_launch(void* const* d_in, const int* in_sizes, int n_in,
                              void* d_out, int out_size, void* d_ws, size_t ws_size,
                              hipStream_t stream) {
  const float* query = (const float*)d_in[0];
  const float* key   = (const float*)d_in[1];
  const float* value = (const float*)d_in[2];
  const float* Wq = (const float*)d_in[3];
  const float* bq = (const float*)d_in[4];
  const float* Wk = (const float*)d_in[5];
  const float* bk = (const float*)d_in[6];
  const float* Wv = (const float*)d_in[7];
  const float* bv = (const float*)d_in[8];
  const float* Wo = (const float*)d_in[9];
  const float* bo = (const float*)d_in[10];
  float* out = (float*)d_out;

  char* ws = (char*)d_ws;
  const size_t WT_BYTES = (size_t)D_ * D_ * sizeof(bf16);   // 2 MB
  const size_t MD_BYTES = (size_t)M_ * D_ * sizeof(bf16);   // 16 MB
  bf16* Wqt  = (bf16*)(ws);
  bf16* Wkt  = (bf16*)(ws + WT_BYTES);
  bf16* Wvt  = (bf16*)(ws + 2 * WT_BYTES);
  bf16* Wot  = (bf16*)(ws + 3 * WT_BYTES);
  bf16* qb   = (bf16*)(ws + 4 * WT_BYTES);
  bf16* kb   = (bf16*)(ws + 4 * WT_BYTES + MD_BYTES);
  bf16* vbT  = (bf16*)(ws + 4 * WT_BYTES + 2 * MD_BYTES);
  bf16* ctxb = (bf16*)(ws + 4 * WT_BYTES + 3 * MD_BYTES);
  // converted activations: qcv aliases ctxb (dead until attn writes it,
  // which is stream-ordered after proj has consumed qcv).
  bf16* qcv  = ctxb;
  bf16* kcv  = (bf16*)(ws + 4 * WT_BYTES + 4 * MD_BYTES);
  bf16* vcv  = (bf16*)(ws + 4 * WT_BYTES + 5 * MD_BYTES);

  wtrans_kernel<<<dim3(D_ / 64, D_ / 64, 4), 256, 0, stream>>>(
      Wq, Wk, Wv, Wo, Wqt, Wkt, Wvt, Wot);

  qkv_cvt_kernel<<<dim3((size_t)M_ * D_ / 2048, 3), 256, 0, stream>>>(
      query, key, value, qcv, kcv, vcv);

  proj_gemm_kernel<<<dim3(D_ / 128, M_ / 128, 3), 256, 0, stream>>>(
      qcv, kcv, vcv, Wqt, Wkt, Wvt, bq, bk, bv, qb, kb, vbT);

  attn_kernel<<<dim3(S_ / 256, B_ * H_), 512, 0, stream>>>(qb, kb, vbT, ctxb);

  out_gemm_kernel<<<dim3(D_ / 128, M_ / 128), 256, 0, stream>>>(ctxb, Wot, bo, out);
}